// Round 11
// baseline (745.390 us; speedup 1.0000x reference)
//
#include <hip/hip_runtime.h>

#define D 32
#define CSH 8                      // 256 nodes per bucket
#define KMASK 255
#define PSH 23                     // payload bits (node id) -> N must be <= 2^23
#define PMASK ((1u << PSH) - 1u)
#define NBMAX 256

typedef unsigned int uint;

// f32 -> bf16 round-to-nearest-even, and pack/unpack helpers
__device__ inline uint bf16rne(float f) {
    uint u = __float_as_uint(f);
    return (u + 0x7FFFu + ((u >> 16) & 1u)) >> 16;
}
__device__ inline float bf_lo(uint w) { return __uint_as_float(w << 16); }
__device__ inline float bf_hi(uint w) { return __uint_as_float(w & 0xFFFF0000u); }
__device__ inline uint bf_pack(float x, float y) { return bf16rne(x) | (bf16rne(y) << 16); }

// ---- zero the bucket cursors ----
__global__ void zero_kernel(int* __restrict__ p, int n) {
    int i = threadIdx.x;
    if (i < n) p[i] = 0;
}

// ---- merged coarse scatter: int4 edge reads, both directions ----
__global__ void coarse_scatter(const int* __restrict__ src, const int* __restrict__ dst,
                               int* __restrict__ gCurD, int* __restrict__ gCurS,
                               uint* __restrict__ coarseD, uint* __restrict__ coarseS,
                               int E, int cap) {
    __shared__ int hD[NBMAX], hS[NBMAX], baseD[NBMAX], baseS[NBMAX];
    int t = threadIdx.x;
    if (t < NBMAX) { hD[t] = 0; hS[t] = 0; }
    __syncthreads();
    int s[4], d[4], lpD[4], lpS[4];
    int j0 = blockIdx.x * 4096 + 4 * t;
    int nv = 0;
    if (j0 + 3 < E) {
        int4 s4 = *(const int4*)(src + j0);
        int4 d4 = *(const int4*)(dst + j0);
        s[0] = s4.x; s[1] = s4.y; s[2] = s4.z; s[3] = s4.w;
        d[0] = d4.x; d[1] = d4.y; d[2] = d4.z; d[3] = d4.w;
        nv = 4;
    } else {
        for (int u = 0; u < 4; ++u) {
            int j = j0 + u;
            if (j < E) { s[nv] = src[j]; d[nv] = dst[j]; ++nv; }
        }
    }
    for (int u = 0; u < nv; ++u) {
        lpD[u] = atomicAdd(&hD[d[u] >> CSH], 1);
        lpS[u] = atomicAdd(&hS[s[u] >> CSH], 1);
    }
    __syncthreads();
    if (t < NBMAX) {
        if (hD[t]) baseD[t] = atomicAdd(&gCurD[t], hD[t]);
        if (hS[t]) baseS[t] = atomicAdd(&gCurS[t], hS[t]);
    }
    __syncthreads();
    for (int u = 0; u < nv; ++u) {
        int bD = d[u] >> CSH, relD = baseD[bD] + lpD[u];
        if (relD < cap)
            coarseD[(size_t)bD * cap + relD] = ((uint)(d[u] & KMASK) << PSH) | (uint)s[u];
        int bS = s[u] >> CSH, relS = baseS[bS] + lpS[u];
        if (relS < cap)
            coarseS[(size_t)bS * cap + relS] = ((uint)(s[u] & KMASK) << PSH) | (uint)d[u];
    }
}

// ---- per-bucket in-degree histogram -> dinv ----
__global__ void deg_dinv_kernel(const uint* __restrict__ coarseD, const int* __restrict__ gCurD,
                                float* __restrict__ dinv, int N, int cap) {
    __shared__ int cnt[256];
    int b = blockIdx.x, t = threadIdx.x;
    if (t < 256) cnt[t] = 0;
    __syncthreads();
    size_t lo = (size_t)b * cap;
    int n = min(gCurD[b], cap);
    int n4 = n >> 2;
    const uint4* c4 = (const uint4*)(coarseD + lo);
    for (int k = t; k < n4; k += 1024) {
        uint4 e = c4[k];
        atomicAdd(&cnt[e.x >> PSH], 1);
        atomicAdd(&cnt[e.y >> PSH], 1);
        atomicAdd(&cnt[e.z >> PSH], 1);
        atomicAdd(&cnt[e.w >> PSH], 1);
    }
    for (int k = 4 * n4 + t; k < n; k += 1024)
        atomicAdd(&cnt[coarseD[lo + k] >> PSH], 1);
    __syncthreads();
    int node = (b << CSH) + t;
    if (t < 256 && node < N) dinv[node] = rsqrtf((float)(cnt[t] + 1));  // +1 self-loop
}

// ---- dense: hs16[i] = bf16((X[i] @ W) * dinv[i]) packed 2/dword ----
__global__ void matmul_scale_kernel(const float* __restrict__ X, const float* __restrict__ W,
                                    const float* __restrict__ dinv, uint* __restrict__ hs16,
                                    int N) {
    __shared__ float Wl[D * D];
    __shared__ float Xl[8 * D];
    int tid = threadIdx.x;
    for (int k = tid; k < D * D; k += 256) Wl[k] = W[k];
    int row0 = blockIdx.x * 8;
    int g = row0 * D + tid;
    Xl[tid] = (g < N * D) ? X[g] : 0.f;
    __syncthreads();
    int r = tid >> 5;
    int d = tid & 31;
    int row = row0 + r;
    float acc = 0.f;
    #pragma unroll
    for (int k = 0; k < D; ++k) acc += Xl[r * D + k] * Wl[k * D + d];
    if (row < N) acc *= dinv[row];
    float other = __shfl_xor(acc, 1);
    if (row < N && (d & 1) == 0)
        hs16[row * 16 + (d >> 1)] = bf_pack(acc, other);
}

// ---- fused conv: stream bucket entries, LDS float-atomic accumulate, finalize relu ----
__global__ void __launch_bounds__(1024)
conv_bucket(const uint* __restrict__ coarseD, const int* __restrict__ gCurD,
            const uint* __restrict__ hs16, const float* __restrict__ dinv,
            const float* __restrict__ bias, uint* __restrict__ h2_16, int N, int cap) {
    __shared__ float acc[256 * 32];   // 32 KB
    int b = blockIdx.x, t = threadIdx.x;
    for (int i = t; i < 256 * 32; i += 1024) acc[i] = 0.f;
    __syncthreads();
    size_t lo = (size_t)b * cap;
    int n = min(gCurD[b], cap);
    int g = t >> 4, p = t & 15;       // 64 groups of 16 lanes
    int kk = 4 * g;
    for (; kk + 3 < n; kk += 256) {
        uint4 e4 = *(const uint4*)(coarseD + lo + kk);
        uint w0 = hs16[(e4.x & PMASK) * 16 + p];
        uint w1 = hs16[(e4.y & PMASK) * 16 + p];
        uint w2 = hs16[(e4.z & PMASK) * 16 + p];
        uint w3 = hs16[(e4.w & PMASK) * 16 + p];
        int d0 = e4.x >> PSH, d1 = e4.y >> PSH, d2 = e4.z >> PSH, d3 = e4.w >> PSH;
        int f0 = (2 * p + d0) & 31, f1 = (2 * p + d1) & 31;
        int f2 = (2 * p + d2) & 31, f3 = (2 * p + d3) & 31;
        atomicAdd(&acc[d0 * 32 + f0], bf_lo(w0));
        atomicAdd(&acc[d0 * 32 + ((f0 + 1) & 31)], bf_hi(w0));
        atomicAdd(&acc[d1 * 32 + f1], bf_lo(w1));
        atomicAdd(&acc[d1 * 32 + ((f1 + 1) & 31)], bf_hi(w1));
        atomicAdd(&acc[d2 * 32 + f2], bf_lo(w2));
        atomicAdd(&acc[d2 * 32 + ((f2 + 1) & 31)], bf_hi(w2));
        atomicAdd(&acc[d3 * 32 + f3], bf_lo(w3));
        atomicAdd(&acc[d3 * 32 + ((f3 + 1) & 31)], bf_hi(w3));
    }
    int tb = n & ~3;
    if (g < n - tb) {                 // tail entries, one per group
        uint e = coarseD[lo + tb + g];
        uint w = hs16[(e & PMASK) * 16 + p];
        int dl = e >> PSH;
        int f0 = (2 * p + dl) & 31;
        atomicAdd(&acc[dl * 32 + f0], bf_lo(w));
        atomicAdd(&acc[dl * 32 + ((f0 + 1) & 31)], bf_hi(w));
    }
    __syncthreads();
    int nodeLo = b << CSH;
    for (int i = t; i < 256 * 16; i += 1024) {
        int dl = i >> 4, pp = i & 15, node = nodeLo + dl;
        if (node < N) {
            int f0 = (2 * pp + dl) & 31;
            float sx = acc[dl * 32 + f0];
            float sy = acc[dl * 32 + ((f0 + 1) & 31)];
            uint ws = hs16[(size_t)node * 16 + pp];
            float di = dinv[node];
            float vx = di * (sx + bf_lo(ws)) + bias[2 * pp];
            float vy = di * (sy + bf_hi(ws)) + bias[2 * pp + 1];
            h2_16[(size_t)node * 16 + pp] = bf_pack(fmaxf(vx, 0.f), fmaxf(vy, 0.f));
        }
    }
}

// ---- fused pow: self rows in LDS, stream entries, finalize tanh(mean) ----
__global__ void __launch_bounds__(1024)
pow_bucket(const uint* __restrict__ coarseS, const int* __restrict__ gCurS,
           const uint* __restrict__ h2_16, float* __restrict__ out, int N, int cap) {
    __shared__ float acc[256 * 32];   // 32 KB
    __shared__ uint self[256 * 16];   // 16 KB
    __shared__ int cnt[256];
    int b = blockIdx.x, t = threadIdx.x;
    for (int i = t; i < 256 * 32; i += 1024) acc[i] = 0.f;
    if (t < 256) cnt[t] = 0;
    int nodeLo = b << CSH;
    for (int i = t; i < 256 * 16; i += 1024) {
        int node = nodeLo + (i >> 4);
        self[i] = (node < N) ? h2_16[(size_t)node * 16 + (i & 15)] : 0u;
    }
    __syncthreads();
    size_t lo = (size_t)b * cap;
    int n = min(gCurS[b], cap);
    int g = t >> 4, p = t & 15;
    int kk = 4 * g;
    for (; kk + 3 < n; kk += 256) {
        uint4 e4 = *(const uint4*)(coarseS + lo + kk);
        uint w0 = h2_16[(e4.x & PMASK) * 16 + p];
        uint w1 = h2_16[(e4.y & PMASK) * 16 + p];
        uint w2 = h2_16[(e4.z & PMASK) * 16 + p];
        uint w3 = h2_16[(e4.w & PMASK) * 16 + p];
        int s0 = e4.x >> PSH, s1 = e4.y >> PSH, s2 = e4.z >> PSH, s3 = e4.w >> PSH;
        uint m0 = self[s0 * 16 + p], m1 = self[s1 * 16 + p];
        uint m2 = self[s2 * 16 + p], m3 = self[s3 * 16 + p];
        float vx0 = bf_lo(m0) - bf_lo(w0), vy0 = bf_hi(m0) - bf_hi(w0);
        float vx1 = bf_lo(m1) - bf_lo(w1), vy1 = bf_hi(m1) - bf_hi(w1);
        float vx2 = bf_lo(m2) - bf_lo(w2), vy2 = bf_hi(m2) - bf_hi(w2);
        float vx3 = bf_lo(m3) - bf_lo(w3), vy3 = bf_hi(m3) - bf_hi(w3);
        int f0 = (2 * p + s0) & 31, f1 = (2 * p + s1) & 31;
        int f2 = (2 * p + s2) & 31, f3 = (2 * p + s3) & 31;
        atomicAdd(&acc[s0 * 32 + f0], vx0 * vx0);
        atomicAdd(&acc[s0 * 32 + ((f0 + 1) & 31)], vy0 * vy0);
        atomicAdd(&acc[s1 * 32 + f1], vx1 * vx1);
        atomicAdd(&acc[s1 * 32 + ((f1 + 1) & 31)], vy1 * vy1);
        atomicAdd(&acc[s2 * 32 + f2], vx2 * vx2);
        atomicAdd(&acc[s2 * 32 + ((f2 + 1) & 31)], vy2 * vy2);
        atomicAdd(&acc[s3 * 32 + f3], vx3 * vx3);
        atomicAdd(&acc[s3 * 32 + ((f3 + 1) & 31)], vy3 * vy3);
        if (p == 0) {
            atomicAdd(&cnt[s0], 1); atomicAdd(&cnt[s1], 1);
            atomicAdd(&cnt[s2], 1); atomicAdd(&cnt[s3], 1);
        }
    }
    int tb = n & ~3;
    if (g < n - tb) {
        uint e = coarseS[lo + tb + g];
        uint w = h2_16[(e & PMASK) * 16 + p];
        int sl = e >> PSH;
        uint m = self[sl * 16 + p];
        float vx = bf_lo(m) - bf_lo(w), vy = bf_hi(m) - bf_hi(w);
        int f0 = (2 * p + sl) & 31;
        atomicAdd(&acc[sl * 32 + f0], vx * vx);
        atomicAdd(&acc[sl * 32 + ((f0 + 1) & 31)], vy * vy);
        if (p == 0) atomicAdd(&cnt[sl], 1);
    }
    __syncthreads();
    for (int i = t; i < 256 * 16; i += 1024) {
        int dl = i >> 4, pp = i & 15, node = nodeLo + dl;
        if (node < N) {
            float c = fmaxf((float)cnt[dl], 1.f);
            int f0 = (2 * pp + dl) & 31;
            float2 r;
            r.x = tanhf(acc[dl * 32 + f0] / c);
            r.y = tanhf(acc[dl * 32 + ((f0 + 1) & 31)] / c);
            ((float2*)out)[(size_t)node * 16 + pp] = r;
        }
    }
}

// ---------------- fallback (atomic path, round-1, all f32) ----------------
__global__ void fb_count(const int* __restrict__ src, const int* __restrict__ dst,
                         int* __restrict__ degI, int* __restrict__ cntI, int E) {
    int j = blockIdx.x * blockDim.x + threadIdx.x;
    if (j < E) {
        atomicAdd(&degI[dst[j]], 1);
        atomicAdd(&cntI[src[j]], 1);
    }
}
__global__ void fb_dinv(const int* __restrict__ degI, float* __restrict__ dinv, int N) {
    int i = blockIdx.x * blockDim.x + threadIdx.x;
    if (i < N) dinv[i] = rsqrtf((float)(degI[i] + 1));
}
__global__ void fb_matmul(const float* __restrict__ X, const float* __restrict__ W,
                          const float* __restrict__ dinv, float* __restrict__ hs, int N) {
    __shared__ float Wl[D * D];
    __shared__ float Xl[8 * D];
    int tid = threadIdx.x;
    for (int k = tid; k < D * D; k += 256) Wl[k] = W[k];
    int row0 = blockIdx.x * 8;
    int g = row0 * D + tid;
    Xl[tid] = (g < N * D) ? X[g] : 0.f;
    __syncthreads();
    int r = tid >> 5;
    int d = tid & 31;
    int row = row0 + r;
    if (row < N) {
        float acc = 0.f;
        #pragma unroll
        for (int k = 0; k < D; ++k) acc += Xl[r * D + k] * Wl[k * D + d];
        hs[row * D + d] = acc * dinv[row];
    }
}
__global__ void fb_scatter_conv(const int* __restrict__ src, const int* __restrict__ dst,
                                const float* __restrict__ hs, float* __restrict__ S, int ED) {
    int idx = blockIdx.x * blockDim.x + threadIdx.x;
    if (idx < ED) {
        int j = idx >> 5, d = idx & 31;
        atomicAdd(&S[dst[j] * D + d], hs[src[j] * D + d]);
    }
}
__global__ void fb_h2(float* __restrict__ S, const float* __restrict__ hs,
                      const float* __restrict__ dinv, const float* __restrict__ b, int ND) {
    int idx = blockIdx.x * blockDim.x + threadIdx.x;
    if (idx < ND) {
        int i = idx >> 5, d = idx & 31;
        float v = dinv[i] * (S[idx] + hs[idx]) + b[d];
        S[idx] = fmaxf(v, 0.f);
    }
}
__global__ void fb_edge_pow(const int* __restrict__ src, const int* __restrict__ dst,
                            const float* __restrict__ h2, float* __restrict__ out, int ED) {
    int idx = blockIdx.x * blockDim.x + threadIdx.x;
    if (idx < ED) {
        int j = idx >> 5, d = idx & 31;
        float v = h2[src[j] * D + d] - h2[dst[j] * D + d];
        atomicAdd(&out[src[j] * D + d], v * v);
    }
}
__global__ void fb_finalize(float* __restrict__ out, const int* __restrict__ cntI, int ND) {
    int idx = blockIdx.x * blockDim.x + threadIdx.x;
    if (idx < ND) {
        int i = idx >> 5;
        float c = fmaxf((float)cntI[i], 1.f);
        out[idx] = tanhf(out[idx] / c);
    }
}

extern "C" void kernel_launch(void* const* d_in, const int* in_sizes, int n_in,
                              void* d_out, int out_size, void* d_ws, size_t ws_size,
                              hipStream_t stream) {
    const float* X  = (const float*)d_in[0];
    const int*   ei = (const int*)d_in[1];
    const float* W  = (const float*)d_in[2];
    const float* b  = (const float*)d_in[3];
    int N = in_sizes[0] / D;
    int E = in_sizes[1] / 2;
    const int* src = ei;
    const int* dst = ei + E;
    float* out = (float*)d_out;

    size_t ND = (size_t)N * D;
    size_t NH = (size_t)N * 16;                   // packed bf16 row = 16 dwords
    int nb = (N + 255) >> CSH;                    // 256-node buckets
    int cap = ((E + nb - 1) / nb + 2048 + 15) & ~15;   // mean + ~22 sigma slack
    size_t capSz = (size_t)nb * cap;

    uint* coarseD = (uint*)d_ws;                  // capSz
    uint* coarseS = coarseD + capSz;              // capSz
    uint* hs16   = coarseS + capSz;               // NH
    uint* h2_16  = hs16 + NH;                     // NH
    float* dinv = (float*)(h2_16 + NH);           // N
    int* gCurD  = (int*)(dinv + N);               // NBMAX
    int* gCurS  = gCurD + NBMAX;                  // NBMAX
    size_t need = (2 * capSz + 2 * NH + (size_t)N + 2 * NBMAX) * 4;

    if (ws_size >= need && nb <= NBMAX && N <= (1 << PSH)) {
        zero_kernel<<<1, 512, 0, stream>>>(gCurD, 2 * NBMAX);   // gCurD+gCurS contiguous
        int cgrid = (E + 4095) / 4096;
        coarse_scatter<<<cgrid, 1024, 0, stream>>>(src, dst, gCurD, gCurS,
                                                   coarseD, coarseS, E, cap);
        deg_dinv_kernel<<<nb, 1024, 0, stream>>>(coarseD, gCurD, dinv, N, cap);
        matmul_scale_kernel<<<(N + 7) / 8, 256, 0, stream>>>(X, W, dinv, hs16, N);
        conv_bucket<<<nb, 1024, 0, stream>>>(coarseD, gCurD, hs16, dinv, b, h2_16, N, cap);
        pow_bucket<<<nb, 1024, 0, stream>>>(coarseS, gCurS, h2_16, out, N, cap);
    } else {
        float* fhs  = (float*)d_ws;
        float* S    = fhs + ND;
        float* fdv  = S + ND;
        int*   fdeg = (int*)(fdv + N);
        int*   fcnt = fdeg + N;
        hipMemsetAsync(S, 0, ND * sizeof(float), stream);
        hipMemsetAsync(fdeg, 0, (size_t)2 * N * sizeof(int), stream);
        hipMemsetAsync(d_out, 0, ND * sizeof(float), stream);
        int EDi = E * D, NDi = (int)ND;
        fb_count<<<(E + 255) / 256, 256, 0, stream>>>(src, dst, fdeg, fcnt, E);
        fb_dinv<<<(N + 255) / 256, 256, 0, stream>>>(fdeg, fdv, N);
        fb_matmul<<<(N + 7) / 8, 256, 0, stream>>>(X, W, fdv, fhs, N);
        fb_scatter_conv<<<(EDi + 255) / 256, 256, 0, stream>>>(src, dst, fhs, S, EDi);
        fb_h2<<<(NDi + 255) / 256, 256, 0, stream>>>(S, fhs, fdv, b, NDi);
        fb_edge_pow<<<(EDi + 255) / 256, 256, 0, stream>>>(src, dst, S, out, EDi);
        fb_finalize<<<(NDi + 255) / 256, 256, 0, stream>>>(out, fcnt, NDi);
    }
}

// Round 12
// 118.639 us; speedup vs baseline: 6.2828x; 6.2828x over previous
//
#include <hip/hip_runtime.h>

#define D 32
#define CSH 8                      // 256 nodes per coarse bucket
#define KMASK 255
#define PSH 23                     // payload bits (node id) -> N must be <= 2^23
#define PMASK ((1u << PSH) - 1u)
#define NBMAX 256

typedef unsigned int uint;

// f32 -> bf16 round-to-nearest-even, and pack/unpack helpers
__device__ inline uint bf16rne(float f) {
    uint u = __float_as_uint(f);
    return (u + 0x7FFFu + ((u >> 16) & 1u)) >> 16;
}
__device__ inline float bf_lo(uint w) { return __uint_as_float(w << 16); }
__device__ inline float bf_hi(uint w) { return __uint_as_float(w & 0xFFFF0000u); }
__device__ inline uint bf_pack(float x, float y) { return bf16rne(x) | (bf16rne(y) << 16); }

// ---- zero the bucket cursors ----
__global__ void zero_kernel(int* __restrict__ p, int n) {
    int i = threadIdx.x;
    if (i < n) p[i] = 0;
}

// ---- merged coarse scatter: int4 edge reads, both directions ----
__global__ void coarse_scatter(const int* __restrict__ src, const int* __restrict__ dst,
                               int* __restrict__ gCurD, int* __restrict__ gCurS,
                               uint* __restrict__ coarseD, uint* __restrict__ coarseS,
                               int E, int cap) {
    __shared__ int hD[NBMAX], hS[NBMAX], baseD[NBMAX], baseS[NBMAX];
    int t = threadIdx.x;
    if (t < NBMAX) { hD[t] = 0; hS[t] = 0; }
    __syncthreads();
    int s[4], d[4], lpD[4], lpS[4];
    int j0 = blockIdx.x * 4096 + 4 * t;     // this thread's 4 consecutive edges
    int nv = 0;
    if (j0 + 3 < E) {
        int4 s4 = *(const int4*)(src + j0);
        int4 d4 = *(const int4*)(dst + j0);
        s[0] = s4.x; s[1] = s4.y; s[2] = s4.z; s[3] = s4.w;
        d[0] = d4.x; d[1] = d4.y; d[2] = d4.z; d[3] = d4.w;
        nv = 4;
    } else {
        for (int u = 0; u < 4; ++u) {
            int j = j0 + u;
            if (j < E) { s[nv] = src[j]; d[nv] = dst[j]; ++nv; }
        }
    }
    for (int u = 0; u < nv; ++u) {
        lpD[u] = atomicAdd(&hD[d[u] >> CSH], 1);
        lpS[u] = atomicAdd(&hS[s[u] >> CSH], 1);
    }
    __syncthreads();
    if (t < NBMAX) {
        if (hD[t]) baseD[t] = atomicAdd(&gCurD[t], hD[t]);
        if (hS[t]) baseS[t] = atomicAdd(&gCurS[t], hS[t]);
    }
    __syncthreads();
    for (int u = 0; u < nv; ++u) {
        int bD = d[u] >> CSH, relD = baseD[bD] + lpD[u];
        if (relD < cap)
            coarseD[(size_t)bD * cap + relD] = ((uint)(d[u] & KMASK) << PSH) | (uint)s[u];
        int bS = s[u] >> CSH, relS = baseS[bS] + lpS[u];
        if (relS < cap)
            coarseS[(size_t)bS * cap + relS] = ((uint)(s[u] & KMASK) << PSH) | (uint)d[u];
    }
}

// ---- fine pass: count(uint4) + 256-wide scan + scatter; rows 4-aligned ----
__global__ void fine_build(const uint* __restrict__ coarseD, const uint* __restrict__ coarseS,
                           const int* __restrict__ gCurD, const int* __restrict__ gCurS,
                           int* __restrict__ rowStartD, int* __restrict__ rowEndD,
                           int* __restrict__ rowStartS, int* __restrict__ rowEndS,
                           int* __restrict__ adjD, int* __restrict__ adjS,
                           float* __restrict__ dinv, int N, int nb, int cap) {
    __shared__ int cnt[256];
    __shared__ int pre[256];
    int which = blockIdx.x >= nb;
    int b = blockIdx.x - which * nb;
    const uint* coarse = which ? coarseS : coarseD;
    const int* gCur = which ? gCurS : gCurD;
    int* rowStart = which ? rowStartS : rowStartD;
    int* rowEnd   = which ? rowEndS : rowEndD;
    int* adj      = which ? adjS : adjD;
    int t = threadIdx.x;   // 1024
    int nodeLo = b << CSH;
    int nNodes = min(256, N - nodeLo);
    if (t < 256) cnt[t] = 0;
    __syncthreads();
    size_t lo = (size_t)b * cap;
    int n = min(gCur[b], cap - 1024);            // clamp so 4-pad can't overflow bucket
    int n4 = n >> 2;
    const uint4* c4 = (const uint4*)(coarse + lo);
    for (int kk = t; kk < n4; kk += 1024) {
        uint4 e4 = c4[kk];
        atomicAdd(&cnt[e4.x >> PSH], 1);
        atomicAdd(&cnt[e4.y >> PSH], 1);
        atomicAdd(&cnt[e4.z >> PSH], 1);
        atomicAdd(&cnt[e4.w >> PSH], 1);
    }
    for (int kk = 4 * n4 + t; kk < n; kk += 1024)
        atomicAdd(&cnt[coarse[lo + kk] >> PSH], 1);
    __syncthreads();
    int mydeg = 0, mypad = 0;
    if (t < 256) { mydeg = cnt[t]; mypad = (mydeg + 3) & ~3; pre[t] = mypad; }
    __syncthreads();
    for (int off = 1; off < 256; off <<= 1) {
        int x = 0;
        if (t < 256 && t >= off) x = pre[t - off];
        __syncthreads();
        if (t < 256) pre[t] += x;
        __syncthreads();
    }
    int myexcl = 0;
    if (t < 256) myexcl = pre[t] - mypad;        // exclusive padded prefix
    if (t < nNodes) {
        rowStart[nodeLo + t] = (int)lo + myexcl;
        rowEnd[nodeLo + t]   = (int)lo + myexcl + mydeg;
        if (!which) dinv[nodeLo + t] = rsqrtf((float)(mydeg + 1));   // +1 self-loop
    }
    __syncthreads();
    if (t < 256) cnt[t] = (int)lo + myexcl;      // cursors
    __syncthreads();
    int hiGuard = (int)lo + cap;
    for (int kk = t; kk < n; kk += 1024) {
        uint e = coarse[lo + kk];
        int pos = atomicAdd(&cnt[e >> PSH], 1);
        if (pos < hiGuard) adj[pos] = (int)(e & PMASK);
    }
}

// ---- dense: hs16[i] = bf16((X[i] @ W) * dinv[i]) packed 2/dword ----
__global__ void matmul_scale_kernel(const float* __restrict__ X, const float* __restrict__ W,
                                    const float* __restrict__ dinv, uint* __restrict__ hs16,
                                    int N) {
    __shared__ float Wl[D * D];
    __shared__ float Xl[8 * D];
    int tid = threadIdx.x;
    for (int k = tid; k < D * D; k += 256) Wl[k] = W[k];
    int row0 = blockIdx.x * 8;
    int g = row0 * D + tid;
    Xl[tid] = (g < N * D) ? X[g] : 0.f;
    __syncthreads();
    int r = tid >> 5;
    int d = tid & 31;
    int row = row0 + r;
    float acc = 0.f;
    #pragma unroll
    for (int k = 0; k < D; ++k) acc += Xl[r * D + k] * Wl[k * D + d];
    if (row < N) acc *= dinv[row];
    float other = __shfl_xor(acc, 1);
    if (row < N && (d & 1) == 0)
        hs16[row * 16 + (d >> 1)] = bf_pack(acc, other);
}

// ---- conv gather: wave per node, lane=(slot 0..3, pair 0..15), int4 adj loads ----
__global__ void conv_gather_kernel(const int* __restrict__ rowStartD, const int* __restrict__ rowEndD,
                                   const int* __restrict__ adjD,
                                   const uint* __restrict__ hs16, const float* __restrict__ dinv,
                                   const float* __restrict__ b, uint* __restrict__ h2_16, int N) {
    int node = blockIdx.x * 8 + (threadIdx.x >> 6);
    if (node >= N) return;
    int lane = threadIdx.x & 63;
    int p = lane & 15;          // feature pair 0..15
    int slot = lane >> 4;       // 0..3
    int s = rowStartD[node], e = rowEndD[node];
    float ax0 = 0.f, ay0 = 0.f, ax1 = 0.f, ay1 = 0.f;
    float ax2 = 0.f, ay2 = 0.f, ax3 = 0.f, ay3 = 0.f;
    int k = s;
    for (; k + 15 < e; k += 16) {
        int4 iv = *(const int4*)(adjD + k + slot * 4);   // s is 4-aligned
        uint w0 = hs16[iv.x * 16 + p];
        uint w1 = hs16[iv.y * 16 + p];
        uint w2 = hs16[iv.z * 16 + p];
        uint w3 = hs16[iv.w * 16 + p];
        ax0 += bf_lo(w0); ay0 += bf_hi(w0);
        ax1 += bf_lo(w1); ay1 += bf_hi(w1);
        ax2 += bf_lo(w2); ay2 += bf_hi(w2);
        ax3 += bf_lo(w3); ay3 += bf_hi(w3);
    }
    for (; k < e; k += 4) {
        int kk = k + slot;
        if (kk < e) {
            uint w = hs16[adjD[kk] * 16 + p];
            ax0 += bf_lo(w); ay0 += bf_hi(w);
        }
    }
    float accx = (ax0 + ax1) + (ax2 + ax3);
    float accy = (ay0 + ay1) + (ay2 + ay3);
    accx += __shfl_xor(accx, 16); accy += __shfl_xor(accy, 16);
    accx += __shfl_xor(accx, 32); accy += __shfl_xor(accy, 32);
    if (slot == 0) {
        uint wself = hs16[node * 16 + p];
        float di = dinv[node];
        float vx = di * (accx + bf_lo(wself)) + b[2 * p];
        float vy = di * (accy + bf_hi(wself)) + b[2 * p + 1];
        h2_16[node * 16 + p] = bf_pack(fmaxf(vx, 0.f), fmaxf(vy, 0.f));
    }
}

// ---- pow gather: out[i] = tanh(mean (h2[i]-h2[dst])^2), f32 output ----
__global__ void pow_gather_kernel(const int* __restrict__ rowStartS, const int* __restrict__ rowEndS,
                                  const int* __restrict__ adjS,
                                  const uint* __restrict__ h2_16, float* __restrict__ out, int N) {
    int node = blockIdx.x * 8 + (threadIdx.x >> 6);
    if (node >= N) return;
    int lane = threadIdx.x & 63;
    int p = lane & 15;
    int slot = lane >> 4;
    int s = rowStartS[node], e = rowEndS[node];
    uint wh = h2_16[node * 16 + p];
    float hx = bf_lo(wh), hy = bf_hi(wh);
    float ax0 = 0.f, ay0 = 0.f, ax1 = 0.f, ay1 = 0.f;
    float ax2 = 0.f, ay2 = 0.f, ax3 = 0.f, ay3 = 0.f;
    int k = s;
    for (; k + 15 < e; k += 16) {
        int4 iv = *(const int4*)(adjS + k + slot * 4);
        uint w0 = h2_16[iv.x * 16 + p];
        uint w1 = h2_16[iv.y * 16 + p];
        uint w2 = h2_16[iv.z * 16 + p];
        uint w3 = h2_16[iv.w * 16 + p];
        float vx0 = hx - bf_lo(w0), vy0 = hy - bf_hi(w0);
        float vx1 = hx - bf_lo(w1), vy1 = hy - bf_hi(w1);
        float vx2 = hx - bf_lo(w2), vy2 = hy - bf_hi(w2);
        float vx3 = hx - bf_lo(w3), vy3 = hy - bf_hi(w3);
        ax0 += vx0 * vx0; ay0 += vy0 * vy0;
        ax1 += vx1 * vx1; ay1 += vy1 * vy1;
        ax2 += vx2 * vx2; ay2 += vy2 * vy2;
        ax3 += vx3 * vx3; ay3 += vy3 * vy3;
    }
    for (; k < e; k += 4) {
        int kk = k + slot;
        if (kk < e) {
            uint w = h2_16[adjS[kk] * 16 + p];
            float vx = hx - bf_lo(w), vy = hy - bf_hi(w);
            ax0 += vx * vx; ay0 += vy * vy;
        }
    }
    float accx = (ax0 + ax1) + (ax2 + ax3);
    float accy = (ay0 + ay1) + (ay2 + ay3);
    accx += __shfl_xor(accx, 16); accy += __shfl_xor(accy, 16);
    accx += __shfl_xor(accx, 32); accy += __shfl_xor(accy, 32);
    if (slot == 0) {
        float c = fmaxf((float)(e - s), 1.f);
        float2 r;
        r.x = tanhf(accx / c);
        r.y = tanhf(accy / c);
        ((float2*)out)[node * 16 + p] = r;
    }
}

// ---------------- fallback (atomic path, round-1, all f32) ----------------
__global__ void fb_count(const int* __restrict__ src, const int* __restrict__ dst,
                         int* __restrict__ degI, int* __restrict__ cntI, int E) {
    int j = blockIdx.x * blockDim.x + threadIdx.x;
    if (j < E) {
        atomicAdd(&degI[dst[j]], 1);
        atomicAdd(&cntI[src[j]], 1);
    }
}
__global__ void fb_dinv(const int* __restrict__ degI, float* __restrict__ dinv, int N) {
    int i = blockIdx.x * blockDim.x + threadIdx.x;
    if (i < N) dinv[i] = rsqrtf((float)(degI[i] + 1));
}
__global__ void fb_matmul(const float* __restrict__ X, const float* __restrict__ W,
                          const float* __restrict__ dinv, float* __restrict__ hs, int N) {
    __shared__ float Wl[D * D];
    __shared__ float Xl[8 * D];
    int tid = threadIdx.x;
    for (int k = tid; k < D * D; k += 256) Wl[k] = W[k];
    int row0 = blockIdx.x * 8;
    int g = row0 * D + tid;
    Xl[tid] = (g < N * D) ? X[g] : 0.f;
    __syncthreads();
    int r = tid >> 5;
    int d = tid & 31;
    int row = row0 + r;
    if (row < N) {
        float acc = 0.f;
        #pragma unroll
        for (int k = 0; k < D; ++k) acc += Xl[r * D + k] * Wl[k * D + d];
        hs[row * D + d] = acc * dinv[row];
    }
}
__global__ void fb_scatter_conv(const int* __restrict__ src, const int* __restrict__ dst,
                                const float* __restrict__ hs, float* __restrict__ S, int ED) {
    int idx = blockIdx.x * blockDim.x + threadIdx.x;
    if (idx < ED) {
        int j = idx >> 5, d = idx & 31;
        atomicAdd(&S[dst[j] * D + d], hs[src[j] * D + d]);
    }
}
__global__ void fb_h2(float* __restrict__ S, const float* __restrict__ hs,
                      const float* __restrict__ dinv, const float* __restrict__ b, int ND) {
    int idx = blockIdx.x * blockDim.x + threadIdx.x;
    if (idx < ND) {
        int i = idx >> 5, d = idx & 31;
        float v = dinv[i] * (S[idx] + hs[idx]) + b[d];
        S[idx] = fmaxf(v, 0.f);
    }
}
__global__ void fb_edge_pow(const int* __restrict__ src, const int* __restrict__ dst,
                            const float* __restrict__ h2, float* __restrict__ out, int ED) {
    int idx = blockIdx.x * blockDim.x + threadIdx.x;
    if (idx < ED) {
        int j = idx >> 5, d = idx & 31;
        float v = h2[src[j] * D + d] - h2[dst[j] * D + d];
        atomicAdd(&out[src[j] * D + d], v * v);
    }
}
__global__ void fb_finalize(float* __restrict__ out, const int* __restrict__ cntI, int ND) {
    int idx = blockIdx.x * blockDim.x + threadIdx.x;
    if (idx < ND) {
        int i = idx >> 5;
        float c = fmaxf((float)cntI[i], 1.f);
        out[idx] = tanhf(out[idx] / c);
    }
}

extern "C" void kernel_launch(void* const* d_in, const int* in_sizes, int n_in,
                              void* d_out, int out_size, void* d_ws, size_t ws_size,
                              hipStream_t stream) {
    const float* X  = (const float*)d_in[0];
    const int*   ei = (const int*)d_in[1];
    const float* W  = (const float*)d_in[2];
    const float* b  = (const float*)d_in[3];
    int N = in_sizes[0] / D;
    int E = in_sizes[1] / 2;
    const int* src = ei;
    const int* dst = ei + E;
    float* out = (float*)d_out;

    size_t ND = (size_t)N * D;
    size_t NH = (size_t)N * 16;                   // packed bf16 row = 16 dwords
    int nb = (N + 255) >> CSH;                    // 256-node buckets
    int cap = ((E + nb - 1) / nb + 2048 + 15) & ~15;   // mean + ~22 sigma slack
    size_t capSz = (size_t)nb * cap;

    uint* coarseD = (uint*)d_ws;                  // capSz
    uint* coarseS = coarseD + capSz;              // capSz
    int* adjD = (int*)(coarseS + capSz);          // capSz
    int* adjS = adjD + capSz;                     // capSz
    uint* hs16   = (uint*)(adjS + capSz);         // NH
    uint* h2_16  = hs16 + NH;                     // NH
    float* dinv = (float*)(h2_16 + NH);           // N
    int* rowStartD = (int*)(dinv + N);            // N
    int* rowEndD   = rowStartD + N;               // N
    int* rowStartS = rowEndD + N;                 // N
    int* rowEndS   = rowStartS + N;               // N
    int* gCurD  = rowEndS + N;                    // NBMAX
    int* gCurS  = gCurD + NBMAX;                  // NBMAX
    size_t need = (4 * capSz + 2 * NH + 5 * (size_t)N + 2 * NBMAX) * 4;

    // capSz indices must fit int (rowStart stored as int)
    if (ws_size >= need && nb <= NBMAX && N <= (1 << PSH) && capSz < (1u << 30)) {
        zero_kernel<<<1, 512, 0, stream>>>(gCurD, 2 * NBMAX);   // gCurD+gCurS contiguous
        int cgrid = (E + 4095) / 4096;
        coarse_scatter<<<cgrid, 1024, 0, stream>>>(src, dst, gCurD, gCurS,
                                                   coarseD, coarseS, E, cap);
        fine_build<<<2 * nb, 1024, 0, stream>>>(coarseD, coarseS, gCurD, gCurS,
                                                rowStartD, rowEndD, rowStartS, rowEndS,
                                                adjD, adjS, dinv, N, nb, cap);
        matmul_scale_kernel<<<(N + 7) / 8, 256, 0, stream>>>(X, W, dinv, hs16, N);
        conv_gather_kernel<<<(N + 7) / 8, 512, 0, stream>>>(rowStartD, rowEndD, adjD,
                                                            hs16, dinv, b, h2_16, N);
        pow_gather_kernel<<<(N + 7) / 8, 512, 0, stream>>>(rowStartS, rowEndS, adjS,
                                                           h2_16, out, N);
    } else {
        float* fhs  = (float*)d_ws;
        float* S    = fhs + ND;
        float* fdv  = S + ND;
        int*   fdeg = (int*)(fdv + N);
        int*   fcnt = fdeg + N;
        hipMemsetAsync(S, 0, ND * sizeof(float), stream);
        hipMemsetAsync(fdeg, 0, (size_t)2 * N * sizeof(int), stream);
        hipMemsetAsync(d_out, 0, ND * sizeof(float), stream);
        int EDi = E * D, NDi = (int)ND;
        fb_count<<<(E + 255) / 256, 256, 0, stream>>>(src, dst, fdeg, fcnt, E);
        fb_dinv<<<(N + 255) / 256, 256, 0, stream>>>(fdeg, fdv, N);
        fb_matmul<<<(N + 7) / 8, 256, 0, stream>>>(X, W, fdv, fhs, N);
        fb_scatter_conv<<<(EDi + 255) / 256, 256, 0, stream>>>(src, dst, fhs, S, EDi);
        fb_h2<<<(NDi + 255) / 256, 256, 0, stream>>>(S, fhs, fdv, b, NDi);
        fb_edge_pow<<<(EDi + 255) / 256, 256, 0, stream>>>(src, dst, S, out, EDi);
        fb_finalize<<<(NDi + 255) / 256, 256, 0, stream>>>(out, fcnt, NDi);
    }
}

// Round 13
// 109.741 us; speedup vs baseline: 6.7922x; 1.0811x over previous
//
#include <hip/hip_runtime.h>

#define D 32
#define CSH 7                      // 128 nodes per coarse bucket
#define KMASK 127
#define PSH 23                     // payload bits (node id) -> N must be <= 2^23
#define PMASK ((1u << PSH) - 1u)
#define NBMAX 512

typedef unsigned int uint;

// f32 -> bf16 round-to-nearest-even, and pack/unpack helpers
__device__ inline uint bf16rne(float f) {
    uint u = __float_as_uint(f);
    return (u + 0x7FFFu + ((u >> 16) & 1u)) >> 16;
}
__device__ inline float bf_lo(uint w) { return __uint_as_float(w << 16); }
__device__ inline float bf_hi(uint w) { return __uint_as_float(w & 0xFFFF0000u); }
__device__ inline uint bf_pack(float x, float y) { return bf16rne(x) | (bf16rne(y) << 16); }

// ---- zero the bucket cursors ----
__global__ void zero_kernel(int* __restrict__ p, int n) {
    int i = threadIdx.x;
    if (i < n) p[i] = 0;
}

// ---- merged coarse scatter: int4 edge reads, both directions ----
__global__ void coarse_scatter(const int* __restrict__ src, const int* __restrict__ dst,
                               int* __restrict__ gCurD, int* __restrict__ gCurS,
                               uint* __restrict__ coarseD, uint* __restrict__ coarseS,
                               int E, int cap) {
    __shared__ int hD[NBMAX], hS[NBMAX], baseD[NBMAX], baseS[NBMAX];
    int t = threadIdx.x;
    if (t < NBMAX) { hD[t] = 0; hS[t] = 0; }
    __syncthreads();
    int s[4], d[4], lpD[4], lpS[4];
    int j0 = blockIdx.x * 4096 + 4 * t;     // this thread's 4 consecutive edges
    int nv = 0;
    if (j0 + 3 < E) {
        int4 s4 = *(const int4*)(src + j0);
        int4 d4 = *(const int4*)(dst + j0);
        s[0] = s4.x; s[1] = s4.y; s[2] = s4.z; s[3] = s4.w;
        d[0] = d4.x; d[1] = d4.y; d[2] = d4.z; d[3] = d4.w;
        nv = 4;
    } else {
        for (int u = 0; u < 4; ++u) {
            int j = j0 + u;
            if (j < E) { s[nv] = src[j]; d[nv] = dst[j]; ++nv; }
        }
    }
    for (int u = 0; u < nv; ++u) {
        lpD[u] = atomicAdd(&hD[d[u] >> CSH], 1);
        lpS[u] = atomicAdd(&hS[s[u] >> CSH], 1);
    }
    __syncthreads();
    if (t < NBMAX) {
        if (hD[t]) baseD[t] = atomicAdd(&gCurD[t], hD[t]);
        if (hS[t]) baseS[t] = atomicAdd(&gCurS[t], hS[t]);
    }
    __syncthreads();
    for (int u = 0; u < nv; ++u) {
        int bD = d[u] >> CSH, relD = baseD[bD] + lpD[u];
        if (relD < cap)
            coarseD[(size_t)bD * cap + relD] = ((uint)(d[u] & KMASK) << PSH) | (uint)s[u];
        int bS = s[u] >> CSH, relS = baseS[bS] + lpS[u];
        if (relS < cap)
            coarseS[(size_t)bS * cap + relS] = ((uint)(s[u] & KMASK) << PSH) | (uint)d[u];
    }
}

// ---- D-direction fine pass: count + 128-wide scan + scatter to global adjD ----
__global__ void fineD_build(const uint* __restrict__ coarseD, const int* __restrict__ gCurD,
                            int* __restrict__ rowStartD, int* __restrict__ rowEndD,
                            int* __restrict__ adjD, float* __restrict__ dinv,
                            int N, int cap) {
    __shared__ int cnt[128];
    __shared__ int pre[128];
    int b = blockIdx.x;
    int t = threadIdx.x;   // 1024
    int nodeLo = b << CSH;
    int nNodes = min(128, N - nodeLo);
    if (t < 128) cnt[t] = 0;
    __syncthreads();
    size_t lo = (size_t)b * cap;
    int n = min(gCurD[b], cap - 512);            // clamp so 4-pad can't overflow bucket
    int n4 = n >> 2;
    const uint4* c4 = (const uint4*)(coarseD + lo);
    for (int kk = t; kk < n4; kk += 1024) {
        uint4 e4 = c4[kk];
        atomicAdd(&cnt[e4.x >> PSH], 1);
        atomicAdd(&cnt[e4.y >> PSH], 1);
        atomicAdd(&cnt[e4.z >> PSH], 1);
        atomicAdd(&cnt[e4.w >> PSH], 1);
    }
    for (int kk = 4 * n4 + t; kk < n; kk += 1024)
        atomicAdd(&cnt[coarseD[lo + kk] >> PSH], 1);
    __syncthreads();
    int mydeg = 0, mypad = 0;
    if (t < 128) { mydeg = cnt[t]; mypad = (mydeg + 3) & ~3; pre[t] = mypad; }
    __syncthreads();
    for (int off = 1; off < 128; off <<= 1) {
        int x = 0;
        if (t < 128 && t >= off) x = pre[t - off];
        __syncthreads();
        if (t < 128) pre[t] += x;
        __syncthreads();
    }
    int myexcl = 0;
    if (t < 128) myexcl = pre[t] - mypad;        // exclusive padded prefix
    if (t < nNodes) {
        rowStartD[nodeLo + t] = (int)lo + myexcl;
        rowEndD[nodeLo + t]   = (int)lo + myexcl + mydeg;
        dinv[nodeLo + t] = rsqrtf((float)(mydeg + 1));   // +1 self-loop
    }
    __syncthreads();
    if (t < 128) cnt[t] = (int)lo + myexcl;      // cursors
    __syncthreads();
    int hiGuard = (int)lo + cap;
    for (int kk = t; kk < n; kk += 1024) {
        uint e = coarseD[lo + kk];
        int pos = atomicAdd(&cnt[e >> PSH], 1);
        if (pos < hiGuard) adjD[pos] = (int)(e & PMASK);
    }
}

// ---- dense: hs16[i] = bf16((X[i] @ W) * dinv[i]) packed 2/dword ----
__global__ void matmul_scale_kernel(const float* __restrict__ X, const float* __restrict__ W,
                                    const float* __restrict__ dinv, uint* __restrict__ hs16,
                                    int N) {
    __shared__ float Wl[D * D];
    __shared__ float Xl[8 * D];
    int tid = threadIdx.x;
    for (int k = tid; k < D * D; k += 256) Wl[k] = W[k];
    int row0 = blockIdx.x * 8;
    int g = row0 * D + tid;
    Xl[tid] = (g < N * D) ? X[g] : 0.f;
    __syncthreads();
    int r = tid >> 5;
    int d = tid & 31;
    int row = row0 + r;
    float acc = 0.f;
    #pragma unroll
    for (int k = 0; k < D; ++k) acc += Xl[r * D + k] * Wl[k * D + d];
    if (row < N) acc *= dinv[row];
    float other = __shfl_xor(acc, 1);
    if (row < N && (d & 1) == 0)
        hs16[row * 16 + (d >> 1)] = bf_pack(acc, other);
}

// ---- conv gather: wave per node, lane=(slot 0..3, pair 0..15), int4 adj loads ----
__global__ void conv_gather_kernel(const int* __restrict__ rowStartD, const int* __restrict__ rowEndD,
                                   const int* __restrict__ adjD,
                                   const uint* __restrict__ hs16, const float* __restrict__ dinv,
                                   const float* __restrict__ b, uint* __restrict__ h2_16, int N) {
    int node = blockIdx.x * 8 + (threadIdx.x >> 6);
    if (node >= N) return;
    int lane = threadIdx.x & 63;
    int p = lane & 15;          // feature pair 0..15
    int slot = lane >> 4;       // 0..3
    int s = rowStartD[node], e = rowEndD[node];
    float ax0 = 0.f, ay0 = 0.f, ax1 = 0.f, ay1 = 0.f;
    float ax2 = 0.f, ay2 = 0.f, ax3 = 0.f, ay3 = 0.f;
    int k = s;
    for (; k + 15 < e; k += 16) {
        int4 iv = *(const int4*)(adjD + k + slot * 4);   // s is 4-aligned
        uint w0 = hs16[iv.x * 16 + p];
        uint w1 = hs16[iv.y * 16 + p];
        uint w2 = hs16[iv.z * 16 + p];
        uint w3 = hs16[iv.w * 16 + p];
        ax0 += bf_lo(w0); ay0 += bf_hi(w0);
        ax1 += bf_lo(w1); ay1 += bf_hi(w1);
        ax2 += bf_lo(w2); ay2 += bf_hi(w2);
        ax3 += bf_lo(w3); ay3 += bf_hi(w3);
    }
    for (; k < e; k += 4) {
        int kk = k + slot;
        if (kk < e) {
            uint w = hs16[adjD[kk] * 16 + p];
            ax0 += bf_lo(w); ay0 += bf_hi(w);
        }
    }
    float accx = (ax0 + ax1) + (ax2 + ax3);
    float accy = (ay0 + ay1) + (ay2 + ay3);
    accx += __shfl_xor(accx, 16); accy += __shfl_xor(accy, 16);
    accx += __shfl_xor(accx, 32); accy += __shfl_xor(accy, 32);
    if (slot == 0) {
        uint wself = hs16[node * 16 + p];
        float di = dinv[node];
        float vx = di * (accx + bf_lo(wself)) + b[2 * p];
        float vy = di * (accy + bf_hi(wself)) + b[2 * p + 1];
        h2_16[node * 16 + p] = bf_pack(fmaxf(vx, 0.f), fmaxf(vy, 0.f));
    }
}

// ---- fused S-direction sort + pow gather; adj lives in LDS, never in global ----
__global__ void __launch_bounds__(1024)
pow_fused(const uint* __restrict__ coarseS, const int* __restrict__ gCurS,
          const uint* __restrict__ h2_16, float* __restrict__ out, int N, int cap) {
    extern __shared__ uint adjL[];               // cap entries (dynamic LDS)
    __shared__ int cnt[128];
    __shared__ int pre[128];
    __shared__ int rs[128];
    __shared__ int degL[128];
    __shared__ uint self[128 * 16];              // 8 KB
    int b = blockIdx.x;
    int t = threadIdx.x;   // 1024
    int nodeLo = b << CSH;
    int nNodes = min(128, N - nodeLo);
    if (t < 128) cnt[t] = 0;
    for (int i = t; i < nNodes * 16; i += 1024)
        self[i] = h2_16[(size_t)(nodeLo + (i >> 4)) * 16 + (i & 15)];
    __syncthreads();
    size_t lo = (size_t)b * cap;
    int n = min(gCurS[b], cap - 512);
    int n4 = n >> 2;
    const uint4* c4 = (const uint4*)(coarseS + lo);
    for (int kk = t; kk < n4; kk += 1024) {
        uint4 e4 = c4[kk];
        atomicAdd(&cnt[e4.x >> PSH], 1);
        atomicAdd(&cnt[e4.y >> PSH], 1);
        atomicAdd(&cnt[e4.z >> PSH], 1);
        atomicAdd(&cnt[e4.w >> PSH], 1);
    }
    for (int kk = 4 * n4 + t; kk < n; kk += 1024)
        atomicAdd(&cnt[coarseS[lo + kk] >> PSH], 1);
    __syncthreads();
    int mydeg = 0, mypad = 0;
    if (t < 128) { mydeg = cnt[t]; mypad = (mydeg + 3) & ~3; pre[t] = mypad; }
    __syncthreads();
    for (int off = 1; off < 128; off <<= 1) {
        int x = 0;
        if (t < 128 && t >= off) x = pre[t - off];
        __syncthreads();
        if (t < 128) pre[t] += x;
        __syncthreads();
    }
    if (t < 128) {
        rs[t] = pre[t] - mypad;                  // 4-aligned relative row start
        degL[t] = mydeg;
        cnt[t] = pre[t] - mypad;                 // cursor
    }
    __syncthreads();
    for (int kk = t; kk < n; kk += 1024) {       // scatter (coarse is L2-hot)
        uint e = coarseS[lo + kk];
        int pos = atomicAdd(&cnt[e >> PSH], 1);
        if (pos < cap) adjL[pos] = e & PMASK;
    }
    __syncthreads();
    // gather phase: wave w handles nodes w, w+16, w+32, ...
    int wave = t >> 6, lane = t & 63;
    int p = lane & 15, slot = lane >> 4;
    for (int nl = wave; nl < nNodes; nl += 16) {
        int s = rs[nl];
        int e = s + degL[nl];
        uint wh = self[nl * 16 + p];
        float hx = bf_lo(wh), hy = bf_hi(wh);
        float ax0 = 0.f, ay0 = 0.f, ax1 = 0.f, ay1 = 0.f;
        float ax2 = 0.f, ay2 = 0.f, ax3 = 0.f, ay3 = 0.f;
        int k = s;
        for (; k + 15 < e; k += 16) {
            uint4 iv = *(const uint4*)(adjL + k + slot * 4);   // LDS b128 read
            uint w0 = h2_16[iv.x * 16 + p];
            uint w1 = h2_16[iv.y * 16 + p];
            uint w2 = h2_16[iv.z * 16 + p];
            uint w3 = h2_16[iv.w * 16 + p];
            float vx0 = hx - bf_lo(w0), vy0 = hy - bf_hi(w0);
            float vx1 = hx - bf_lo(w1), vy1 = hy - bf_hi(w1);
            float vx2 = hx - bf_lo(w2), vy2 = hy - bf_hi(w2);
            float vx3 = hx - bf_lo(w3), vy3 = hy - bf_hi(w3);
            ax0 += vx0 * vx0; ay0 += vy0 * vy0;
            ax1 += vx1 * vx1; ay1 += vy1 * vy1;
            ax2 += vx2 * vx2; ay2 += vy2 * vy2;
            ax3 += vx3 * vx3; ay3 += vy3 * vy3;
        }
        for (; k < e; k += 4) {
            int kk = k + slot;
            if (kk < e) {
                uint w = h2_16[adjL[kk] * 16 + p];
                float vx = hx - bf_lo(w), vy = hy - bf_hi(w);
                ax0 += vx * vx; ay0 += vy * vy;
            }
        }
        float accx = (ax0 + ax1) + (ax2 + ax3);
        float accy = (ay0 + ay1) + (ay2 + ay3);
        accx += __shfl_xor(accx, 16); accy += __shfl_xor(accy, 16);
        accx += __shfl_xor(accx, 32); accy += __shfl_xor(accy, 32);
        if (slot == 0) {
            float c = fmaxf((float)degL[nl], 1.f);
            float2 r;
            r.x = tanhf(accx / c);
            r.y = tanhf(accy / c);
            ((float2*)out)[(size_t)(nodeLo + nl) * 16 + p] = r;
        }
    }
}

// ---------------- fallback (atomic path, round-1, all f32) ----------------
__global__ void fb_count(const int* __restrict__ src, const int* __restrict__ dst,
                         int* __restrict__ degI, int* __restrict__ cntI, int E) {
    int j = blockIdx.x * blockDim.x + threadIdx.x;
    if (j < E) {
        atomicAdd(&degI[dst[j]], 1);
        atomicAdd(&cntI[src[j]], 1);
    }
}
__global__ void fb_dinv(const int* __restrict__ degI, float* __restrict__ dinv, int N) {
    int i = blockIdx.x * blockDim.x + threadIdx.x;
    if (i < N) dinv[i] = rsqrtf((float)(degI[i] + 1));
}
__global__ void fb_matmul(const float* __restrict__ X, const float* __restrict__ W,
                          const float* __restrict__ dinv, float* __restrict__ hs, int N) {
    __shared__ float Wl[D * D];
    __shared__ float Xl[8 * D];
    int tid = threadIdx.x;
    for (int k = tid; k < D * D; k += 256) Wl[k] = W[k];
    int row0 = blockIdx.x * 8;
    int g = row0 * D + tid;
    Xl[tid] = (g < N * D) ? X[g] : 0.f;
    __syncthreads();
    int r = tid >> 5;
    int d = tid & 31;
    int row = row0 + r;
    if (row < N) {
        float acc = 0.f;
        #pragma unroll
        for (int k = 0; k < D; ++k) acc += Xl[r * D + k] * Wl[k * D + d];
        hs[row * D + d] = acc * dinv[row];
    }
}
__global__ void fb_scatter_conv(const int* __restrict__ src, const int* __restrict__ dst,
                                const float* __restrict__ hs, float* __restrict__ S, int ED) {
    int idx = blockIdx.x * blockDim.x + threadIdx.x;
    if (idx < ED) {
        int j = idx >> 5, d = idx & 31;
        atomicAdd(&S[dst[j] * D + d], hs[src[j] * D + d]);
    }
}
__global__ void fb_h2(float* __restrict__ S, const float* __restrict__ hs,
                      const float* __restrict__ dinv, const float* __restrict__ b, int ND) {
    int idx = blockIdx.x * blockDim.x + threadIdx.x;
    if (idx < ND) {
        int i = idx >> 5, d = idx & 31;
        float v = dinv[i] * (S[idx] + hs[idx]) + b[d];
        S[idx] = fmaxf(v, 0.f);
    }
}
__global__ void fb_edge_pow(const int* __restrict__ src, const int* __restrict__ dst,
                            const float* __restrict__ h2, float* __restrict__ out, int ED) {
    int idx = blockIdx.x * blockDim.x + threadIdx.x;
    if (idx < ED) {
        int j = idx >> 5, d = idx & 31;
        float v = h2[src[j] * D + d] - h2[dst[j] * D + d];
        atomicAdd(&out[src[j] * D + d], v * v);
    }
}
__global__ void fb_finalize(float* __restrict__ out, const int* __restrict__ cntI, int ND) {
    int idx = blockIdx.x * blockDim.x + threadIdx.x;
    if (idx < ND) {
        int i = idx >> 5;
        float c = fmaxf((float)cntI[i], 1.f);
        out[idx] = tanhf(out[idx] / c);
    }
}

extern "C" void kernel_launch(void* const* d_in, const int* in_sizes, int n_in,
                              void* d_out, int out_size, void* d_ws, size_t ws_size,
                              hipStream_t stream) {
    const float* X  = (const float*)d_in[0];
    const int*   ei = (const int*)d_in[1];
    const float* W  = (const float*)d_in[2];
    const float* b  = (const float*)d_in[3];
    int N = in_sizes[0] / D;
    int E = in_sizes[1] / 2;
    const int* src = ei;
    const int* dst = ei + E;
    float* out = (float*)d_out;

    size_t ND = (size_t)N * D;
    size_t NH = (size_t)N * 16;                   // packed bf16 row = 16 dwords
    int nb = (N + 127) >> CSH;                    // 128-node buckets
    int cap = ((E + nb - 1) / nb + 1024 + 15) & ~15;   // mean + ~16 sigma slack
    size_t capSz = (size_t)nb * cap;
    size_t ldsBytes = (size_t)cap * 4;            // pow_fused dynamic LDS

    uint* coarseD = (uint*)d_ws;                  // capSz
    uint* coarseS = coarseD + capSz;              // capSz
    int* adjD = (int*)(coarseS + capSz);          // capSz
    uint* hs16   = (uint*)(adjD + capSz);         // NH
    uint* h2_16  = hs16 + NH;                     // NH
    float* dinv = (float*)(h2_16 + NH);           // N
    int* rowStartD = (int*)(dinv + N);            // N
    int* rowEndD   = rowStartD + N;               // N
    int* gCurD  = rowEndD + N;                    // NBMAX
    int* gCurS  = gCurD + NBMAX;                  // NBMAX
    size_t need = (3 * capSz + 2 * NH + 3 * (size_t)N + 2 * NBMAX) * 4;

    if (ws_size >= need && nb <= NBMAX && N <= (1 << PSH) && capSz < (1u << 30)
        && ldsBytes <= 96 * 1024) {
        zero_kernel<<<1, 1024, 0, stream>>>(gCurD, 2 * NBMAX);   // gCurD+gCurS contiguous
        int cgrid = (E + 4095) / 4096;
        coarse_scatter<<<cgrid, 1024, 0, stream>>>(src, dst, gCurD, gCurS,
                                                   coarseD, coarseS, E, cap);
        fineD_build<<<nb, 1024, 0, stream>>>(coarseD, gCurD, rowStartD, rowEndD,
                                             adjD, dinv, N, cap);
        matmul_scale_kernel<<<(N + 7) / 8, 256, 0, stream>>>(X, W, dinv, hs16, N);
        conv_gather_kernel<<<(N + 7) / 8, 512, 0, stream>>>(rowStartD, rowEndD, adjD,
                                                            hs16, dinv, b, h2_16, N);
        pow_fused<<<nb, 1024, ldsBytes, stream>>>(coarseS, gCurS, h2_16, out, N, cap);
    } else {
        float* fhs  = (float*)d_ws;
        float* S    = fhs + ND;
        float* fdv  = S + ND;
        int*   fdeg = (int*)(fdv + N);
        int*   fcnt = fdeg + N;
        hipMemsetAsync(S, 0, ND * sizeof(float), stream);
        hipMemsetAsync(fdeg, 0, (size_t)2 * N * sizeof(int), stream);
        hipMemsetAsync(d_out, 0, ND * sizeof(float), stream);
        int EDi = E * D, NDi = (int)ND;
        fb_count<<<(E + 255) / 256, 256, 0, stream>>>(src, dst, fdeg, fcnt, E);
        fb_dinv<<<(N + 255) / 256, 256, 0, stream>>>(fdeg, fdv, N);
        fb_matmul<<<(N + 7) / 8, 256, 0, stream>>>(X, W, fdv, fhs, N);
        fb_scatter_conv<<<(EDi + 255) / 256, 256, 0, stream>>>(src, dst, fhs, S, EDi);
        fb_h2<<<(NDi + 255) / 256, 256, 0, stream>>>(S, fhs, fdv, b, NDi);
        fb_edge_pow<<<(EDi + 255) / 256, 256, 0, stream>>>(src, dst, S, out, EDi);
        fb_finalize<<<(NDi + 255) / 256, 256, 0, stream>>>(out, fcnt, NDi);
    }
}

// Round 14
// 98.184 us; speedup vs baseline: 7.5918x; 1.1177x over previous
//
#include <hip/hip_runtime.h>

#define D 32
#define CSH 7                      // 128 nodes per coarse bucket
#define KMASK 127
#define PSH 23                     // payload bits (node id) -> N must be <= 2^23
#define PMASK ((1u << PSH) - 1u)
#define NBMAX 512

typedef unsigned int uint;

// f32 -> bf16 round-to-nearest-even, and pack/unpack helpers
__device__ inline uint bf16rne(float f) {
    uint u = __float_as_uint(f);
    return (u + 0x7FFFu + ((u >> 16) & 1u)) >> 16;
}
__device__ inline float bf_lo(uint w) { return __uint_as_float(w << 16); }
__device__ inline float bf_hi(uint w) { return __uint_as_float(w & 0xFFFF0000u); }
__device__ inline uint bf_pack(float x, float y) { return bf16rne(x) | (bf16rne(y) << 16); }

// ---- zero the bucket cursors ----
__global__ void zero_kernel(int* __restrict__ p, int n) {
    int i = threadIdx.x;
    if (i < n) p[i] = 0;
}

// ---- merged coarse scatter: int4 edge reads, both directions ----
__global__ void coarse_scatter(const int* __restrict__ src, const int* __restrict__ dst,
                               int* __restrict__ gCurD, int* __restrict__ gCurS,
                               uint* __restrict__ coarseD, uint* __restrict__ coarseS,
                               int E, int cap) {
    __shared__ int hD[NBMAX], hS[NBMAX], baseD[NBMAX], baseS[NBMAX];
    int t = threadIdx.x;
    if (t < NBMAX) { hD[t] = 0; hS[t] = 0; }
    __syncthreads();
    int s[4], d[4], lpD[4], lpS[4];
    int j0 = blockIdx.x * 4096 + 4 * t;     // this thread's 4 consecutive edges
    int nv = 0;
    if (j0 + 3 < E) {
        int4 s4 = *(const int4*)(src + j0);
        int4 d4 = *(const int4*)(dst + j0);
        s[0] = s4.x; s[1] = s4.y; s[2] = s4.z; s[3] = s4.w;
        d[0] = d4.x; d[1] = d4.y; d[2] = d4.z; d[3] = d4.w;
        nv = 4;
    } else {
        for (int u = 0; u < 4; ++u) {
            int j = j0 + u;
            if (j < E) { s[nv] = src[j]; d[nv] = dst[j]; ++nv; }
        }
    }
    for (int u = 0; u < nv; ++u) {
        lpD[u] = atomicAdd(&hD[d[u] >> CSH], 1);
        lpS[u] = atomicAdd(&hS[s[u] >> CSH], 1);
    }
    __syncthreads();
    if (t < NBMAX) {
        if (hD[t]) baseD[t] = atomicAdd(&gCurD[t], hD[t]);
        if (hS[t]) baseS[t] = atomicAdd(&gCurS[t], hS[t]);
    }
    __syncthreads();
    for (int u = 0; u < nv; ++u) {
        int bD = d[u] >> CSH, relD = baseD[bD] + lpD[u];
        if (relD < cap)
            coarseD[(size_t)bD * cap + relD] = ((uint)(d[u] & KMASK) << PSH) | (uint)s[u];
        int bS = s[u] >> CSH, relS = baseS[bS] + lpS[u];
        if (relS < cap)
            coarseS[(size_t)bS * cap + relS] = ((uint)(s[u] & KMASK) << PSH) | (uint)d[u];
    }
}

// ---- per-bucket in-degree histogram -> dinv (no scatter) ----
__global__ void deg_dinv_kernel(const uint* __restrict__ coarseD, const int* __restrict__ gCurD,
                                float* __restrict__ dinv, int N, int cap) {
    __shared__ int cnt[128];
    int b = blockIdx.x, t = threadIdx.x;   // 1024
    if (t < 128) cnt[t] = 0;
    __syncthreads();
    size_t lo = (size_t)b * cap;
    int n = min(gCurD[b], cap - 512);
    int n4 = n >> 2;
    const uint4* c4 = (const uint4*)(coarseD + lo);
    for (int kk = t; kk < n4; kk += 1024) {
        uint4 e4 = c4[kk];
        atomicAdd(&cnt[e4.x >> PSH], 1);
        atomicAdd(&cnt[e4.y >> PSH], 1);
        atomicAdd(&cnt[e4.z >> PSH], 1);
        atomicAdd(&cnt[e4.w >> PSH], 1);
    }
    for (int kk = 4 * n4 + t; kk < n; kk += 1024)
        atomicAdd(&cnt[coarseD[lo + kk] >> PSH], 1);
    __syncthreads();
    int node = (b << CSH) + t;
    if (t < 128 && node < N) dinv[node] = rsqrtf((float)(cnt[t] + 1));  // +1 self-loop
}

// ---- dense: hs16[i] = bf16((X[i] @ W) * dinv[i]) packed 2/dword ----
__global__ void matmul_scale_kernel(const float* __restrict__ X, const float* __restrict__ W,
                                    const float* __restrict__ dinv, uint* __restrict__ hs16,
                                    int N) {
    __shared__ float Wl[D * D];
    __shared__ float Xl[8 * D];
    int tid = threadIdx.x;
    for (int k = tid; k < D * D; k += 256) Wl[k] = W[k];
    int row0 = blockIdx.x * 8;
    int g = row0 * D + tid;
    Xl[tid] = (g < N * D) ? X[g] : 0.f;
    __syncthreads();
    int r = tid >> 5;
    int d = tid & 31;
    int row = row0 + r;
    float acc = 0.f;
    #pragma unroll
    for (int k = 0; k < D; ++k) acc += Xl[r * D + k] * Wl[k * D + d];
    if (row < N) acc *= dinv[row];
    float other = __shfl_xor(acc, 1);
    if (row < N && (d & 1) == 0)
        hs16[row * 16 + (d >> 1)] = bf_pack(acc, other);
}

// ---- fused D-direction sort + conv gather; adj lives in LDS, never in global ----
__global__ void __launch_bounds__(1024)
conv_fused(const uint* __restrict__ coarseD, const int* __restrict__ gCurD,
           const uint* __restrict__ hs16, const float* __restrict__ bias,
           uint* __restrict__ h2_16, int N, int cap) {
    extern __shared__ uint adjL[];               // cap entries (dynamic LDS)
    __shared__ int cnt[128];
    __shared__ int pre[128];
    __shared__ int rs[128];
    __shared__ int degL[128];
    int b = blockIdx.x;
    int t = threadIdx.x;   // 1024
    int nodeLo = b << CSH;
    int nNodes = min(128, N - nodeLo);
    if (t < 128) cnt[t] = 0;
    __syncthreads();
    size_t lo = (size_t)b * cap;
    int n = min(gCurD[b], cap - 512);
    int n4 = n >> 2;
    const uint4* c4 = (const uint4*)(coarseD + lo);
    for (int kk = t; kk < n4; kk += 1024) {
        uint4 e4 = c4[kk];
        atomicAdd(&cnt[e4.x >> PSH], 1);
        atomicAdd(&cnt[e4.y >> PSH], 1);
        atomicAdd(&cnt[e4.z >> PSH], 1);
        atomicAdd(&cnt[e4.w >> PSH], 1);
    }
    for (int kk = 4 * n4 + t; kk < n; kk += 1024)
        atomicAdd(&cnt[coarseD[lo + kk] >> PSH], 1);
    __syncthreads();
    int mydeg = 0, mypad = 0;
    if (t < 128) { mydeg = cnt[t]; mypad = (mydeg + 3) & ~3; pre[t] = mypad; }
    __syncthreads();
    for (int off = 1; off < 128; off <<= 1) {
        int x = 0;
        if (t < 128 && t >= off) x = pre[t - off];
        __syncthreads();
        if (t < 128) pre[t] += x;
        __syncthreads();
    }
    if (t < 128) {
        rs[t] = pre[t] - mypad;                  // 4-aligned relative row start
        degL[t] = mydeg;
        cnt[t] = pre[t] - mypad;                 // cursor
    }
    __syncthreads();
    for (int kk = t; kk < n; kk += 1024) {       // scatter (coarse is L2-hot)
        uint e = coarseD[lo + kk];
        int pos = atomicAdd(&cnt[e >> PSH], 1);
        if (pos < cap) adjL[pos] = e & PMASK;
    }
    __syncthreads();
    // gather phase: wave w handles nodes w, w+16, w+32, ...
    int wave = t >> 6, lane = t & 63;
    int p = lane & 15, slot = lane >> 4;
    for (int nl = wave; nl < nNodes; nl += 16) {
        int s = rs[nl];
        int e = s + degL[nl];
        float ax0 = 0.f, ay0 = 0.f, ax1 = 0.f, ay1 = 0.f;
        float ax2 = 0.f, ay2 = 0.f, ax3 = 0.f, ay3 = 0.f;
        int k = s;
        for (; k + 15 < e; k += 16) {
            uint4 iv = *(const uint4*)(adjL + k + slot * 4);   // LDS b128 read
            uint w0 = hs16[iv.x * 16 + p];
            uint w1 = hs16[iv.y * 16 + p];
            uint w2 = hs16[iv.z * 16 + p];
            uint w3 = hs16[iv.w * 16 + p];
            ax0 += bf_lo(w0); ay0 += bf_hi(w0);
            ax1 += bf_lo(w1); ay1 += bf_hi(w1);
            ax2 += bf_lo(w2); ay2 += bf_hi(w2);
            ax3 += bf_lo(w3); ay3 += bf_hi(w3);
        }
        for (; k < e; k += 4) {
            int kk = k + slot;
            if (kk < e) {
                uint w = hs16[adjL[kk] * 16 + p];
                ax0 += bf_lo(w); ay0 += bf_hi(w);
            }
        }
        float accx = (ax0 + ax1) + (ax2 + ax3);
        float accy = (ay0 + ay1) + (ay2 + ay3);
        accx += __shfl_xor(accx, 16); accy += __shfl_xor(accy, 16);
        accx += __shfl_xor(accx, 32); accy += __shfl_xor(accy, 32);
        if (slot == 0) {
            int node = nodeLo + nl;
            uint wself = hs16[(size_t)node * 16 + p];
            float di = rsqrtf((float)(degL[nl] + 1));
            float vx = di * (accx + bf_lo(wself)) + bias[2 * p];
            float vy = di * (accy + bf_hi(wself)) + bias[2 * p + 1];
            h2_16[(size_t)node * 16 + p] = bf_pack(fmaxf(vx, 0.f), fmaxf(vy, 0.f));
        }
    }
}

// ---- fused S-direction sort + pow gather; adj lives in LDS, never in global ----
__global__ void __launch_bounds__(1024)
pow_fused(const uint* __restrict__ coarseS, const int* __restrict__ gCurS,
          const uint* __restrict__ h2_16, float* __restrict__ out, int N, int cap) {
    extern __shared__ uint adjL[];               // cap entries (dynamic LDS)
    __shared__ int cnt[128];
    __shared__ int pre[128];
    __shared__ int rs[128];
    __shared__ int degL[128];
    __shared__ uint self[128 * 16];              // 8 KB
    int b = blockIdx.x;
    int t = threadIdx.x;   // 1024
    int nodeLo = b << CSH;
    int nNodes = min(128, N - nodeLo);
    if (t < 128) cnt[t] = 0;
    for (int i = t; i < nNodes * 16; i += 1024)
        self[i] = h2_16[(size_t)(nodeLo + (i >> 4)) * 16 + (i & 15)];
    __syncthreads();
    size_t lo = (size_t)b * cap;
    int n = min(gCurS[b], cap - 512);
    int n4 = n >> 2;
    const uint4* c4 = (const uint4*)(coarseS + lo);
    for (int kk = t; kk < n4; kk += 1024) {
        uint4 e4 = c4[kk];
        atomicAdd(&cnt[e4.x >> PSH], 1);
        atomicAdd(&cnt[e4.y >> PSH], 1);
        atomicAdd(&cnt[e4.z >> PSH], 1);
        atomicAdd(&cnt[e4.w >> PSH], 1);
    }
    for (int kk = 4 * n4 + t; kk < n; kk += 1024)
        atomicAdd(&cnt[coarseS[lo + kk] >> PSH], 1);
    __syncthreads();
    int mydeg = 0, mypad = 0;
    if (t < 128) { mydeg = cnt[t]; mypad = (mydeg + 3) & ~3; pre[t] = mypad; }
    __syncthreads();
    for (int off = 1; off < 128; off <<= 1) {
        int x = 0;
        if (t < 128 && t >= off) x = pre[t - off];
        __syncthreads();
        if (t < 128) pre[t] += x;
        __syncthreads();
    }
    if (t < 128) {
        rs[t] = pre[t] - mypad;                  // 4-aligned relative row start
        degL[t] = mydeg;
        cnt[t] = pre[t] - mypad;                 // cursor
    }
    __syncthreads();
    for (int kk = t; kk < n; kk += 1024) {       // scatter (coarse is L2-hot)
        uint e = coarseS[lo + kk];
        int pos = atomicAdd(&cnt[e >> PSH], 1);
        if (pos < cap) adjL[pos] = e & PMASK;
    }
    __syncthreads();
    // gather phase: wave w handles nodes w, w+16, w+32, ...
    int wave = t >> 6, lane = t & 63;
    int p = lane & 15, slot = lane >> 4;
    for (int nl = wave; nl < nNodes; nl += 16) {
        int s = rs[nl];
        int e = s + degL[nl];
        uint wh = self[nl * 16 + p];
        float hx = bf_lo(wh), hy = bf_hi(wh);
        float ax0 = 0.f, ay0 = 0.f, ax1 = 0.f, ay1 = 0.f;
        float ax2 = 0.f, ay2 = 0.f, ax3 = 0.f, ay3 = 0.f;
        int k = s;
        for (; k + 15 < e; k += 16) {
            uint4 iv = *(const uint4*)(adjL + k + slot * 4);   // LDS b128 read
            uint w0 = h2_16[iv.x * 16 + p];
            uint w1 = h2_16[iv.y * 16 + p];
            uint w2 = h2_16[iv.z * 16 + p];
            uint w3 = h2_16[iv.w * 16 + p];
            float vx0 = hx - bf_lo(w0), vy0 = hy - bf_hi(w0);
            float vx1 = hx - bf_lo(w1), vy1 = hy - bf_hi(w1);
            float vx2 = hx - bf_lo(w2), vy2 = hy - bf_hi(w2);
            float vx3 = hx - bf_lo(w3), vy3 = hy - bf_hi(w3);
            ax0 += vx0 * vx0; ay0 += vy0 * vy0;
            ax1 += vx1 * vx1; ay1 += vy1 * vy1;
            ax2 += vx2 * vx2; ay2 += vy2 * vy2;
            ax3 += vx3 * vx3; ay3 += vy3 * vy3;
        }
        for (; k < e; k += 4) {
            int kk = k + slot;
            if (kk < e) {
                uint w = h2_16[adjL[kk] * 16 + p];
                float vx = hx - bf_lo(w), vy = hy - bf_hi(w);
                ax0 += vx * vx; ay0 += vy * vy;
            }
        }
        float accx = (ax0 + ax1) + (ax2 + ax3);
        float accy = (ay0 + ay1) + (ay2 + ay3);
        accx += __shfl_xor(accx, 16); accy += __shfl_xor(accy, 16);
        accx += __shfl_xor(accx, 32); accy += __shfl_xor(accy, 32);
        if (slot == 0) {
            float c = fmaxf((float)degL[nl], 1.f);
            float2 r;
            r.x = tanhf(accx / c);
            r.y = tanhf(accy / c);
            ((float2*)out)[(size_t)(nodeLo + nl) * 16 + p] = r;
        }
    }
}

// ---------------- fallback (atomic path, round-1, all f32) ----------------
__global__ void fb_count(const int* __restrict__ src, const int* __restrict__ dst,
                         int* __restrict__ degI, int* __restrict__ cntI, int E) {
    int j = blockIdx.x * blockDim.x + threadIdx.x;
    if (j < E) {
        atomicAdd(&degI[dst[j]], 1);
        atomicAdd(&cntI[src[j]], 1);
    }
}
__global__ void fb_dinv(const int* __restrict__ degI, float* __restrict__ dinv, int N) {
    int i = blockIdx.x * blockDim.x + threadIdx.x;
    if (i < N) dinv[i] = rsqrtf((float)(degI[i] + 1));
}
__global__ void fb_matmul(const float* __restrict__ X, const float* __restrict__ W,
                          const float* __restrict__ dinv, float* __restrict__ hs, int N) {
    __shared__ float Wl[D * D];
    __shared__ float Xl[8 * D];
    int tid = threadIdx.x;
    for (int k = tid; k < D * D; k += 256) Wl[k] = W[k];
    int row0 = blockIdx.x * 8;
    int g = row0 * D + tid;
    Xl[tid] = (g < N * D) ? X[g] : 0.f;
    __syncthreads();
    int r = tid >> 5;
    int d = tid & 31;
    int row = row0 + r;
    if (row < N) {
        float acc = 0.f;
        #pragma unroll
        for (int k = 0; k < D; ++k) acc += Xl[r * D + k] * Wl[k * D + d];
        hs[row * D + d] = acc * dinv[row];
    }
}
__global__ void fb_scatter_conv(const int* __restrict__ src, const int* __restrict__ dst,
                                const float* __restrict__ hs, float* __restrict__ S, int ED) {
    int idx = blockIdx.x * blockDim.x + threadIdx.x;
    if (idx < ED) {
        int j = idx >> 5, d = idx & 31;
        atomicAdd(&S[dst[j] * D + d], hs[src[j] * D + d]);
    }
}
__global__ void fb_h2(float* __restrict__ S, const float* __restrict__ hs,
                      const float* __restrict__ dinv, const float* __restrict__ b, int ND) {
    int idx = blockIdx.x * blockDim.x + threadIdx.x;
    if (idx < ND) {
        int i = idx >> 5, d = idx & 31;
        float v = dinv[i] * (S[idx] + hs[idx]) + b[d];
        S[idx] = fmaxf(v, 0.f);
    }
}
__global__ void fb_edge_pow(const int* __restrict__ src, const int* __restrict__ dst,
                            const float* __restrict__ h2, float* __restrict__ out, int ED) {
    int idx = blockIdx.x * blockDim.x + threadIdx.x;
    if (idx < ED) {
        int j = idx >> 5, d = idx & 31;
        float v = h2[src[j] * D + d] - h2[dst[j] * D + d];
        atomicAdd(&out[src[j] * D + d], v * v);
    }
}
__global__ void fb_finalize(float* __restrict__ out, const int* __restrict__ cntI, int ND) {
    int idx = blockIdx.x * blockDim.x + threadIdx.x;
    if (idx < ND) {
        int i = idx >> 5;
        float c = fmaxf((float)cntI[i], 1.f);
        out[idx] = tanhf(out[idx] / c);
    }
}

extern "C" void kernel_launch(void* const* d_in, const int* in_sizes, int n_in,
                              void* d_out, int out_size, void* d_ws, size_t ws_size,
                              hipStream_t stream) {
    const float* X  = (const float*)d_in[0];
    const int*   ei = (const int*)d_in[1];
    const float* W  = (const float*)d_in[2];
    const float* b  = (const float*)d_in[3];
    int N = in_sizes[0] / D;
    int E = in_sizes[1] / 2;
    const int* src = ei;
    const int* dst = ei + E;
    float* out = (float*)d_out;

    size_t ND = (size_t)N * D;
    size_t NH = (size_t)N * 16;                   // packed bf16 row = 16 dwords
    int nb = (N + 127) >> CSH;                    // 128-node buckets
    int cap = ((E + nb - 1) / nb + 1024 + 15) & ~15;   // mean + ~16 sigma slack
    size_t capSz = (size_t)nb * cap;
    size_t ldsBytes = (size_t)cap * 4;            // fused kernels' dynamic LDS

    uint* coarseD = (uint*)d_ws;                  // capSz
    uint* coarseS = coarseD + capSz;              // capSz
    uint* hs16   = coarseS + capSz;               // NH
    uint* h2_16  = hs16 + NH;                     // NH
    float* dinv = (float*)(h2_16 + NH);           // N
    int* gCurD  = (int*)(dinv + N);               // NBMAX
    int* gCurS  = gCurD + NBMAX;                  // NBMAX
    size_t need = (2 * capSz + 2 * NH + (size_t)N + 2 * NBMAX) * 4;

    if (ws_size >= need && nb <= NBMAX && N <= (1 << PSH) && capSz < (1u << 30)
        && ldsBytes <= 96 * 1024) {
        zero_kernel<<<1, 1024, 0, stream>>>(gCurD, 2 * NBMAX);   // gCurD+gCurS contiguous
        int cgrid = (E + 4095) / 4096;
        coarse_scatter<<<cgrid, 1024, 0, stream>>>(src, dst, gCurD, gCurS,
                                                   coarseD, coarseS, E, cap);
        deg_dinv_kernel<<<nb, 1024, 0, stream>>>(coarseD, gCurD, dinv, N, cap);
        matmul_scale_kernel<<<(N + 7) / 8, 256, 0, stream>>>(X, W, dinv, hs16, N);
        conv_fused<<<nb, 1024, ldsBytes, stream>>>(coarseD, gCurD, hs16, b, h2_16, N, cap);
        pow_fused<<<nb, 1024, ldsBytes, stream>>>(coarseS, gCurS, h2_16, out, N, cap);
    } else {
        float* fhs  = (float*)d_ws;
        float* S    = fhs + ND;
        float* fdv  = S + ND;
        int*   fdeg = (int*)(fdv + N);
        int*   fcnt = fdeg + N;
        hipMemsetAsync(S, 0, ND * sizeof(float), stream);
        hipMemsetAsync(fdeg, 0, (size_t)2 * N * sizeof(int), stream);
        hipMemsetAsync(d_out, 0, ND * sizeof(float), stream);
        int EDi = E * D, NDi = (int)ND;
        fb_count<<<(E + 255) / 256, 256, 0, stream>>>(src, dst, fdeg, fcnt, E);
        fb_dinv<<<(N + 255) / 256, 256, 0, stream>>>(fdeg, fdv, N);
        fb_matmul<<<(N + 7) / 8, 256, 0, stream>>>(X, W, fdv, fhs, N);
        fb_scatter_conv<<<(EDi + 255) / 256, 256, 0, stream>>>(src, dst, fhs, S, EDi);
        fb_h2<<<(NDi + 255) / 256, 256, 0, stream>>>(S, fhs, fdv, b, NDi);
        fb_edge_pow<<<(EDi + 255) / 256, 256, 0, stream>>>(src, dst, S, out, EDi);
        fb_finalize<<<(NDi + 255) / 256, 256, 0, stream>>>(out, fcnt, NDi);
    }
}